// Round 6
// baseline (282.672 us; speedup 1.0000x reference)
//
#include <hip/hip_runtime.h>

#define BSHIFT 10
#define BSZ (1 << BSHIFT)          // 1024 nodes per bucket
#define NBMAX 1024
#define NBIN_BLOCKS 1024           // histogram/placement chunks
#define PB 512                     // k_place2 threads
#define BATCH 8192                 // edges sorted per LDS batch

// ---------------- node-map kernels ----------------

__global__ void k1b(const float* __restrict__ feat, const float* __restrict__ norm,
                    float* __restrict__ g1, int n) {
    int stride = gridDim.x * blockDim.x;
    for (int i = blockIdx.x * blockDim.x + threadIdx.x; i < n; i += stride)
        g1[i] = feat[i] * norm[i];
}

// fallback path helpers
__global__ void k1_prep(const float* __restrict__ feat, const float* __restrict__ norm,
                        float* __restrict__ g1, float* __restrict__ agg1,
                        float* __restrict__ agg2, int n) {
    int stride = gridDim.x * blockDim.x;
    for (int i = blockIdx.x * blockDim.x + threadIdx.x; i < n; i += stride) {
        g1[i] = feat[i] * norm[i];
        agg1[i] = 0.0f;
        agg2[i] = 0.0f;
    }
}

__global__ void k3_mid(const float* __restrict__ agg1, const float* __restrict__ norm,
                       const float* __restrict__ W1, const float* __restrict__ b1,
                       const float* __restrict__ W2, float* __restrict__ t, int n) {
    float w10 = W1[0], w11 = W1[1], w12 = W1[2];
    float b10 = b1[0], b11 = b1[1], b12 = b1[2];
    float w20 = W2[0], w21 = W2[1], w22 = W2[2];
    int stride = gridDim.x * blockDim.x;
    for (int i = blockIdx.x * blockDim.x + threadIdx.x; i < n; i += stride) {
        float nv = norm[i];
        float s = agg1[i] * nv;
        float h0 = fmaxf(fmaf(s, w10, b10), 0.0f);
        float h1 = fmaxf(fmaf(s, w11, b11), 0.0f);
        float h2 = fmaxf(fmaf(s, w12, b12), 0.0f);
        t[i] = nv * (h0 * w20 + h1 * w21 + h2 * w22);
    }
}

__global__ void k5_out(const float* __restrict__ agg2, const float* __restrict__ norm,
                       const float* __restrict__ b2, float* __restrict__ out, int n) {
    float b = b2[0];
    int stride = gridDim.x * blockDim.x;
    for (int i = blockIdx.x * blockDim.x + threadIdx.x; i < n; i += stride)
        out[i] = fmaxf(agg2[i] * norm[i] + b, 0.0f);
}

// ---------------- binning pipeline ----------------

// H: per-chunk LDS histogram -> counts[b * NBIN_BLOCKS + chunk]  (transposed)
__global__ void k_hist(const int* __restrict__ dst, int nE, int NB, int chunk,
                       int* __restrict__ counts) {
    extern __shared__ int lhist[];
    int t = threadIdx.x;
    for (int b = t; b < NB; b += blockDim.x) lhist[b] = 0;
    __syncthreads();
    int lo = blockIdx.x * chunk;
    int hi = min(lo + chunk, nE);
    int n4 = (hi - lo) >> 2;                       // lo % 4 == 0 (chunk % 4 == 0)
    const int4* d4 = (const int4*)(dst + lo);
    for (int i = t; i < n4; i += blockDim.x) {
        int4 v = d4[i];
        atomicAdd(&lhist[v.x >> BSHIFT], 1);
        atomicAdd(&lhist[v.y >> BSHIFT], 1);
        atomicAdd(&lhist[v.z >> BSHIFT], 1);
        atomicAdd(&lhist[v.w >> BSHIFT], 1);
    }
    for (int i = lo + (n4 << 2) + t; i < hi; i += blockDim.x)
        atomicAdd(&lhist[dst[i] >> BSHIFT], 1);
    __syncthreads();
    for (int b = t; b < NB; b += blockDim.x)
        counts[(size_t)b * NBIN_BLOCKS + blockIdx.x] = lhist[b];
}

// S1: one block per bucket — exclusive scan of its 1024 chunk counts.
__global__ void k_bucketscan(const int* __restrict__ counts,
                             int* __restrict__ chunkpre, int* __restrict__ tot) {
    __shared__ int ssum[256];
    int b = blockIdx.x;
    int t = threadIdx.x;
    const int4* in4 = (const int4*)(counts + (size_t)b * NBIN_BLOCKS);
    int4 v = in4[t];
    int mysum = v.x + v.y + v.z + v.w;
    ssum[t] = mysum;
    __syncthreads();
    for (int ofs = 1; ofs < 256; ofs <<= 1) {
        int add = (t >= ofs) ? ssum[t - ofs] : 0;
        __syncthreads();
        ssum[t] += add;
        __syncthreads();
    }
    int excl = ssum[t] - mysum;
    int4 o;
    o.x = excl;
    o.y = excl + v.x;
    o.z = o.y + v.y;
    o.w = o.z + v.z;
    ((int4*)(chunkpre + (size_t)b * NBIN_BLOCKS))[t] = o;
    if (t == 255) tot[b] = ssum[255];
}

// S2: exclusive scan over NB bucket totals -> base[0..NB]
__global__ void k_exscan(const int* __restrict__ tot, int NB, int* __restrict__ base) {
    __shared__ int s[1024];
    int t = threadIdx.x;
    if (NB < 1024) {
        int v = (t < NB) ? tot[t] : 0;
        s[t] = v;
        __syncthreads();
        for (int ofs = 1; ofs < 1024; ofs <<= 1) {
            int add = (t >= ofs) ? s[t - ofs] : 0;
            __syncthreads();
            s[t] += add;
            __syncthreads();
        }
        if (t < NB) base[t] = s[t] - v;
        if (t == NB) base[NB] = s[NB - 1];
    } else if (t == 0) {
        int run = 0;
        for (int b = 0; b < NB; ++b) { base[b] = run; run += tot[b]; }
        base[NB] = run;
    }
}

// P2: LDS-sorted placement; bucket id recorded per slot (no binary search).
// Handles up to NBMAX=1024 buckets with PB=512 threads (2 entries/thread scan).
__global__ void __launch_bounds__(PB)
k_place2(const int* __restrict__ src, const int* __restrict__ dst,
         int nE, int NB, int chunk,
         const int* __restrict__ chunkpre, const int* __restrict__ base,
         unsigned int* __restrict__ bpack) {
    __shared__ unsigned int spack[BATCH];      // 32 KB sorted packed edges
    __shared__ unsigned short sbkt[BATCH];     // 16 KB bucket id per slot
    __shared__ int lcur[NBMAX];                // 4 KB
    __shared__ int loff[NBMAX + 1];            // 4 KB
    __shared__ int gcur[NBMAX];                // 4 KB
    __shared__ int ssc[PB];                    // 2 KB
    int t = threadIdx.x;
    int blk = blockIdx.x;

    for (int b = t; b < NB; b += PB)
        gcur[b] = base[b] + chunkpre[(size_t)b * NBIN_BLOCKS + blk];

    int lo = blk * chunk;
    int hi = min(lo + chunk, nE);
    for (int bs = lo; bs < hi; bs += BATCH) {
        int be = min(bs + BATCH, hi);
        int cnt = be - bs;
        lcur[2 * t] = 0;
        lcur[2 * t + 1] = 0;
        __syncthreads();
        // phase A: batch histogram (int4 loads; bs % 4 == 0)
        int n4 = cnt >> 2;
        const int4* d4 = (const int4*)(dst + bs);
        for (int i = t; i < n4; i += PB) {
            int4 v = d4[i];
            atomicAdd(&lcur[v.x >> BSHIFT], 1);
            atomicAdd(&lcur[v.y >> BSHIFT], 1);
            atomicAdd(&lcur[v.z >> BSHIFT], 1);
            atomicAdd(&lcur[v.w >> BSHIFT], 1);
        }
        for (int i = bs + (n4 << 2) + t; i < be; i += PB)
            atomicAdd(&lcur[dst[i] >> BSHIFT], 1);
        __syncthreads();
        // scan 1024 entries with 512 threads (pair per thread)
        int a = lcur[2 * t];
        int c = lcur[2 * t + 1];
        int s = a + c;
        ssc[t] = s;
        __syncthreads();
        for (int ofs = 1; ofs < PB; ofs <<= 1) {
            int add = (t >= ofs) ? ssc[t - ofs] : 0;
            __syncthreads();
            ssc[t] += add;
            __syncthreads();
        }
        int excl = ssc[t] - s;
        loff[2 * t] = excl;
        loff[2 * t + 1] = excl + a;
        lcur[2 * t] = excl;
        lcur[2 * t + 1] = excl + a;
        if (t == PB - 1) loff[2 * PB] = ssc[PB - 1];
        __syncthreads();
        // phase B: sorted scatter into LDS (int4 loads of src+dst)
        const int4* s4 = (const int4*)(src + bs);
        for (int i = t; i < n4; i += PB) {
            int4 dv = d4[i];
            int4 sv = s4[i];
            int b0 = dv.x >> BSHIFT, p0 = atomicAdd(&lcur[b0], 1);
            spack[p0] = ((unsigned int)sv.x << BSHIFT) | (unsigned int)(dv.x & (BSZ - 1));
            sbkt[p0] = (unsigned short)b0;
            int b1 = dv.y >> BSHIFT, p1 = atomicAdd(&lcur[b1], 1);
            spack[p1] = ((unsigned int)sv.y << BSHIFT) | (unsigned int)(dv.y & (BSZ - 1));
            sbkt[p1] = (unsigned short)b1;
            int b2 = dv.z >> BSHIFT, p2 = atomicAdd(&lcur[b2], 1);
            spack[p2] = ((unsigned int)sv.z << BSHIFT) | (unsigned int)(dv.z & (BSZ - 1));
            sbkt[p2] = (unsigned short)b2;
            int b3 = dv.w >> BSHIFT, p3 = atomicAdd(&lcur[b3], 1);
            spack[p3] = ((unsigned int)sv.w << BSHIFT) | (unsigned int)(dv.w & (BSZ - 1));
            sbkt[p3] = (unsigned short)b3;
        }
        for (int i = bs + (n4 << 2) + t; i < be; i += PB) {
            int d = dst[i];
            int b = d >> BSHIFT;
            int pos = atomicAdd(&lcur[b], 1);
            spack[pos] = ((unsigned int)src[i] << BSHIFT) | (unsigned int)(d & (BSZ - 1));
            sbkt[pos] = (unsigned short)b;
        }
        __syncthreads();
        // flush: direct bucket lookup, per-bucket contiguous global segments
        for (int j = t; j < cnt; j += PB) {
            int b = sbkt[j];
            bpack[gcur[b] + (j - loff[b])] = spack[j];
        }
        __syncthreads();
        for (int b = t; b < NB; b += PB)
            gcur[b] += loff[b + 1] - loff[b];
        __syncthreads();
    }
}

// shared accumulate body: stream bpack (2x uint4 unroll = 8 gathers in flight)
__device__ __forceinline__ void acc_body(const unsigned int* __restrict__ bpack,
                                         int lo, int hi,
                                         const float* __restrict__ val,
                                         float* acc) {
    int head = min((4 - (lo & 3)) & 3, hi - lo);
    for (int i = lo + (int)threadIdx.x; i < lo + head; i += blockDim.x) {
        unsigned int w = bpack[i];
        atomicAdd(&acc[w & (BSZ - 1)], val[w >> BSHIFT]);
    }
    int lo4 = lo + head;
    int n4 = (hi - lo4) >> 2;
    const uint4* p4 = (const uint4*)(bpack + lo4);
    int i = threadIdx.x;
    int bd = blockDim.x;
    for (; i + bd < n4; i += 2 * bd) {
        uint4 wa = p4[i];
        uint4 wb = p4[i + bd];
        float va0 = val[wa.x >> BSHIFT], va1 = val[wa.y >> BSHIFT];
        float va2 = val[wa.z >> BSHIFT], va3 = val[wa.w >> BSHIFT];
        float vb0 = val[wb.x >> BSHIFT], vb1 = val[wb.y >> BSHIFT];
        float vb2 = val[wb.z >> BSHIFT], vb3 = val[wb.w >> BSHIFT];
        atomicAdd(&acc[wa.x & (BSZ - 1)], va0);
        atomicAdd(&acc[wa.y & (BSZ - 1)], va1);
        atomicAdd(&acc[wa.z & (BSZ - 1)], va2);
        atomicAdd(&acc[wa.w & (BSZ - 1)], va3);
        atomicAdd(&acc[wb.x & (BSZ - 1)], vb0);
        atomicAdd(&acc[wb.y & (BSZ - 1)], vb1);
        atomicAdd(&acc[wb.z & (BSZ - 1)], vb2);
        atomicAdd(&acc[wb.w & (BSZ - 1)], vb3);
    }
    for (; i < n4; i += bd) {
        uint4 w = p4[i];
        atomicAdd(&acc[w.x & (BSZ - 1)], val[w.x >> BSHIFT]);
        atomicAdd(&acc[w.y & (BSZ - 1)], val[w.y >> BSHIFT]);
        atomicAdd(&acc[w.z & (BSZ - 1)], val[w.z >> BSHIFT]);
        atomicAdd(&acc[w.w & (BSZ - 1)], val[w.w >> BSHIFT]);
    }
    for (int j = lo4 + (n4 << 2) + (int)threadIdx.x; j < hi; j += blockDim.x) {
        unsigned int w = bpack[j];
        atomicAdd(&acc[w & (BSZ - 1)], val[w >> BSHIFT]);
    }
}

// A1: bucket accumulate of g1 + fused layer-1 MLP -> t[node]
__global__ void k_acc1(const unsigned int* __restrict__ bpack,
                       const int* __restrict__ base,
                       const float* __restrict__ val, const float* __restrict__ norm,
                       const float* __restrict__ W1, const float* __restrict__ b1,
                       const float* __restrict__ W2,
                       float* __restrict__ t, int nN) {
    __shared__ float acc[BSZ];
    for (int j = threadIdx.x; j < BSZ; j += blockDim.x) acc[j] = 0.0f;
    __syncthreads();
    int b = blockIdx.x;
    acc_body(bpack, base[b], base[b + 1], val, acc);
    __syncthreads();
    float w10 = W1[0], w11 = W1[1], w12 = W1[2];
    float b10 = b1[0], b11 = b1[1], b12 = b1[2];
    float w20 = W2[0], w21 = W2[1], w22 = W2[2];
    int node0 = b << BSHIFT;
    for (int j = threadIdx.x; j < BSZ && node0 + j < nN; j += blockDim.x) {
        float nv = norm[node0 + j];
        float s = acc[j] * nv;
        float h0 = fmaxf(fmaf(s, w10, b10), 0.0f);
        float h1 = fmaxf(fmaf(s, w11, b11), 0.0f);
        float h2 = fmaxf(fmaf(s, w12, b12), 0.0f);
        t[node0 + j] = nv * (h0 * w20 + h1 * w21 + h2 * w22);
    }
}

// A2: bucket accumulate of t + fused output relu -> out[node]
__global__ void k_acc2(const unsigned int* __restrict__ bpack,
                       const int* __restrict__ base,
                       const float* __restrict__ val, const float* __restrict__ norm,
                       const float* __restrict__ b2,
                       float* __restrict__ out, int nN) {
    __shared__ float acc[BSZ];
    for (int j = threadIdx.x; j < BSZ; j += blockDim.x) acc[j] = 0.0f;
    __syncthreads();
    int b = blockIdx.x;
    acc_body(bpack, base[b], base[b + 1], val, acc);
    __syncthreads();
    float bb = b2[0];
    int node0 = b << BSHIFT;
    for (int j = threadIdx.x; j < BSZ && node0 + j < nN; j += blockDim.x)
        out[node0 + j] = fmaxf(acc[j] * norm[node0 + j] + bb, 0.0f);
}

// ---------------- fallback: direct device-scope atomic scatter ----------------
__global__ void k_edge_scatter(const int* __restrict__ src, const int* __restrict__ dst,
                               const float* __restrict__ val, float* __restrict__ agg,
                               int nE) {
    int stride = gridDim.x * blockDim.x;
    for (int e = blockIdx.x * blockDim.x + threadIdx.x; e < nE; e += stride)
        atomicAdd(&agg[dst[e]], val[src[e]]);
}

static inline size_t align256(size_t x) { return (x + 255) & ~(size_t)255; }

extern "C" void kernel_launch(void* const* d_in, const int* in_sizes, int n_in,
                              void* d_out, int out_size, void* d_ws, size_t ws_size,
                              hipStream_t stream) {
    const float* feat = (const float*)d_in[0];
    const float* norm = (const float*)d_in[1];
    const int*   src  = (const int*)d_in[2];
    const int*   dst  = (const int*)d_in[3];
    const float* W1   = (const float*)d_in[4];
    const float* b1   = (const float*)d_in[5];
    const float* W2   = (const float*)d_in[6];
    const float* b2   = (const float*)d_in[7];
    float* out = (float*)d_out;

    int nN = in_sizes[0];
    int nE = in_sizes[2];
    int NB = (nN + BSZ - 1) >> BSHIFT;

    // workspace layout (agg2 unions with counts: fallback-only vs binned-only)
    char* p = (char*)d_ws;
    size_t off = 0;
    float* g1   = (float*)(p + off); off = align256(off + (size_t)nN * 4);
    float* agg1 = (float*)(p + off); off = align256(off + (size_t)nN * 4);
    int* base     = (int*)(p + off); off = align256(off + (size_t)(NB + 1) * 4);
    int* tot      = (int*)(p + off); off = align256(off + (size_t)NB * 4);
    float* agg2   = (float*)(p + off);                        // fallback only
    int* counts   = (int*)(p + off); off = align256(off + (size_t)NB * NBIN_BLOCKS * 4);
    int* chunkpre = (int*)(p + off); off = align256(off + (size_t)NB * NBIN_BLOCKS * 4);
    unsigned int* bpack = (unsigned int*)(p + off); off = align256(off + (size_t)nE * 4);
    size_t need = off;

    const int BLK = 256;
    int nodeBlocks = (nN + BLK - 1) / BLK;
    if (nodeBlocks > 2048) nodeBlocks = 2048;

    bool packed_ok = ((size_t)nN <= ((size_t)1 << (32 - BSHIFT))) && (NB <= NBMAX);
    if (ws_size >= need && packed_ok) {
        // chunk: multiple of 4 so int4 loads stay aligned
        int chunk = (nE + NBIN_BLOCKS - 1) / NBIN_BLOCKS;
        chunk = (chunk + 3) & ~3;
        size_t ldsNB = (size_t)NB * 4;

        k1b<<<nodeBlocks, BLK, 0, stream>>>(feat, norm, g1, nN);
        k_hist<<<NBIN_BLOCKS, 256, ldsNB, stream>>>(dst, nE, NB, chunk, counts);
        k_bucketscan<<<NB, 256, 0, stream>>>(counts, chunkpre, tot);
        k_exscan<<<1, 1024, 0, stream>>>(tot, NB, base);
        k_place2<<<NBIN_BLOCKS, PB, 0, stream>>>(src, dst, nE, NB, chunk,
                                                 chunkpre, base, bpack);
        k_acc1<<<NB, 512, 0, stream>>>(bpack, base, g1, norm, W1, b1, W2, agg1, nN);
        k_acc2<<<NB, 512, 0, stream>>>(bpack, base, agg1, norm, b2, out, nN);
    } else {
        // fallback: direct atomic scatter (round-1 path)
        int edgeBlocks = 2048;
        k1_prep<<<nodeBlocks, BLK, 0, stream>>>(feat, norm, g1, agg1, agg2, nN);
        k_edge_scatter<<<edgeBlocks, BLK, 0, stream>>>(src, dst, g1, agg1, nE);
        k3_mid<<<nodeBlocks, BLK, 0, stream>>>(agg1, norm, W1, b1, W2, g1, nN);
        k_edge_scatter<<<edgeBlocks, BLK, 0, stream>>>(src, dst, g1, agg2, nE);
        k5_out<<<nodeBlocks, BLK, 0, stream>>>(agg2, norm, b2, out, nN);
    }
}

// Round 7
// 274.552 us; speedup vs baseline: 1.0296x; 1.0296x over previous
//
#include <hip/hip_runtime.h>

#define BSHIFT 11
#define BSZ (1 << BSHIFT)          // 2048 nodes per bucket
#define NBMAX 512
#define NBIN_BLOCKS 1024           // histogram/placement chunks
#define PB 512                     // k_place2 threads
#define BATCH 8192                 // edges sorted per LDS batch

// ---------------- node-map kernels ----------------

__global__ void k1b(const float* __restrict__ feat, const float* __restrict__ norm,
                    float* __restrict__ g1, int n) {
    int stride = gridDim.x * blockDim.x;
    for (int i = blockIdx.x * blockDim.x + threadIdx.x; i < n; i += stride)
        g1[i] = feat[i] * norm[i];
}

// fallback path helpers
__global__ void k1_prep(const float* __restrict__ feat, const float* __restrict__ norm,
                        float* __restrict__ g1, float* __restrict__ agg1,
                        float* __restrict__ agg2, int n) {
    int stride = gridDim.x * blockDim.x;
    for (int i = blockIdx.x * blockDim.x + threadIdx.x; i < n; i += stride) {
        g1[i] = feat[i] * norm[i];
        agg1[i] = 0.0f;
        agg2[i] = 0.0f;
    }
}

__global__ void k3_mid(const float* __restrict__ agg1, const float* __restrict__ norm,
                       const float* __restrict__ W1, const float* __restrict__ b1,
                       const float* __restrict__ W2, float* __restrict__ t, int n) {
    float w10 = W1[0], w11 = W1[1], w12 = W1[2];
    float b10 = b1[0], b11 = b1[1], b12 = b1[2];
    float w20 = W2[0], w21 = W2[1], w22 = W2[2];
    int stride = gridDim.x * blockDim.x;
    for (int i = blockIdx.x * blockDim.x + threadIdx.x; i < n; i += stride) {
        float nv = norm[i];
        float s = agg1[i] * nv;
        float h0 = fmaxf(fmaf(s, w10, b10), 0.0f);
        float h1 = fmaxf(fmaf(s, w11, b11), 0.0f);
        float h2 = fmaxf(fmaf(s, w12, b12), 0.0f);
        t[i] = nv * (h0 * w20 + h1 * w21 + h2 * w22);
    }
}

__global__ void k5_out(const float* __restrict__ agg2, const float* __restrict__ norm,
                       const float* __restrict__ b2, float* __restrict__ out, int n) {
    float b = b2[0];
    int stride = gridDim.x * blockDim.x;
    for (int i = blockIdx.x * blockDim.x + threadIdx.x; i < n; i += stride)
        out[i] = fmaxf(agg2[i] * norm[i] + b, 0.0f);
}

// ---------------- binning pipeline ----------------

// H: per-chunk LDS histogram -> counts[b * NBIN_BLOCKS + chunk]  (transposed)
__global__ void k_hist(const int* __restrict__ dst, int nE, int NB, int chunk,
                       int* __restrict__ counts) {
    extern __shared__ int lhist[];
    int t = threadIdx.x;
    for (int b = t; b < NB; b += blockDim.x) lhist[b] = 0;
    __syncthreads();
    int lo = blockIdx.x * chunk;
    int hi = min(lo + chunk, nE);
    int n4 = (hi - lo) >> 2;                       // lo % 4 == 0 (chunk % 4 == 0)
    const int4* d4 = (const int4*)(dst + lo);
    for (int i = t; i < n4; i += blockDim.x) {
        int4 v = d4[i];
        atomicAdd(&lhist[v.x >> BSHIFT], 1);
        atomicAdd(&lhist[v.y >> BSHIFT], 1);
        atomicAdd(&lhist[v.z >> BSHIFT], 1);
        atomicAdd(&lhist[v.w >> BSHIFT], 1);
    }
    for (int i = lo + (n4 << 2) + t; i < hi; i += blockDim.x)
        atomicAdd(&lhist[dst[i] >> BSHIFT], 1);
    __syncthreads();
    for (int b = t; b < NB; b += blockDim.x)
        counts[(size_t)b * NBIN_BLOCKS + blockIdx.x] = lhist[b];
}

// S1: one block per bucket — exclusive scan of its 1024 chunk counts.
__global__ void k_bucketscan(const int* __restrict__ counts,
                             int* __restrict__ chunkpre, int* __restrict__ tot) {
    __shared__ int ssum[256];
    int b = blockIdx.x;
    int t = threadIdx.x;
    const int4* in4 = (const int4*)(counts + (size_t)b * NBIN_BLOCKS);
    int4 v = in4[t];
    int mysum = v.x + v.y + v.z + v.w;
    ssum[t] = mysum;
    __syncthreads();
    for (int ofs = 1; ofs < 256; ofs <<= 1) {
        int add = (t >= ofs) ? ssum[t - ofs] : 0;
        __syncthreads();
        ssum[t] += add;
        __syncthreads();
    }
    int excl = ssum[t] - mysum;
    int4 o;
    o.x = excl;
    o.y = excl + v.x;
    o.z = o.y + v.y;
    o.w = o.z + v.z;
    ((int4*)(chunkpre + (size_t)b * NBIN_BLOCKS))[t] = o;
    if (t == 255) tot[b] = ssum[255];
}

// S2: exclusive scan over NB bucket totals -> base[0..NB]
__global__ void k_exscan(const int* __restrict__ tot, int NB, int* __restrict__ base) {
    __shared__ int s[1024];
    int t = threadIdx.x;
    if (NB < 1024) {
        int v = (t < NB) ? tot[t] : 0;
        s[t] = v;
        __syncthreads();
        for (int ofs = 1; ofs < 1024; ofs <<= 1) {
            int add = (t >= ofs) ? s[t - ofs] : 0;
            __syncthreads();
            s[t] += add;
            __syncthreads();
        }
        if (t < NB) base[t] = s[t] - v;
        if (t == NB) base[NB] = s[NB - 1];
    } else if (t == 0) {
        int run = 0;
        for (int b = 0; b < NB; ++b) { base[b] = run; run += tot[b]; }
        base[NB] = run;
    }
}

// P2: LDS-sorted placement; bucket id recorded per slot (no binary search).
// NB <= 512; scan one entry per thread.
__global__ void __launch_bounds__(PB)
k_place2(const int* __restrict__ src, const int* __restrict__ dst,
         int nE, int NB, int chunk,
         const int* __restrict__ chunkpre, const int* __restrict__ base,
         unsigned int* __restrict__ bpack) {
    __shared__ unsigned int spack[BATCH];      // 32 KB sorted packed edges
    __shared__ unsigned short sbkt[BATCH];     // 16 KB bucket id per slot
    __shared__ int lcur[NBMAX];
    __shared__ int loff[NBMAX + 1];
    __shared__ int gcur[NBMAX];
    __shared__ int ssc[NBMAX];
    int t = threadIdx.x;
    int blk = blockIdx.x;

    for (int b = t; b < NB; b += PB)
        gcur[b] = base[b] + chunkpre[(size_t)b * NBIN_BLOCKS + blk];

    int lo = blk * chunk;
    int hi = min(lo + chunk, nE);
    for (int bs = lo; bs < hi; bs += BATCH) {
        int be = min(bs + BATCH, hi);
        int cnt = be - bs;
        lcur[t] = 0;
        __syncthreads();
        // phase A: batch histogram (int4 loads; bs % 4 == 0)
        int n4 = cnt >> 2;
        const int4* d4 = (const int4*)(dst + bs);
        for (int i = t; i < n4; i += PB) {
            int4 v = d4[i];
            atomicAdd(&lcur[v.x >> BSHIFT], 1);
            atomicAdd(&lcur[v.y >> BSHIFT], 1);
            atomicAdd(&lcur[v.z >> BSHIFT], 1);
            atomicAdd(&lcur[v.w >> BSHIFT], 1);
        }
        for (int i = bs + (n4 << 2) + t; i < be; i += PB)
            atomicAdd(&lcur[dst[i] >> BSHIFT], 1);
        __syncthreads();
        // scan 512 (Hillis-Steele inclusive) -> exclusive offsets
        int v = lcur[t];
        ssc[t] = v;
        __syncthreads();
        for (int ofs = 1; ofs < 512; ofs <<= 1) {
            int add = (t >= ofs) ? ssc[t - ofs] : 0;
            __syncthreads();
            ssc[t] += add;
            __syncthreads();
        }
        int excl = ssc[t] - v;
        loff[t] = excl;
        lcur[t] = excl;
        if (t == 511) loff[512] = ssc[511];
        __syncthreads();
        // phase B: sorted scatter into LDS (int4 loads of src+dst)
        const int4* s4 = (const int4*)(src + bs);
        for (int i = t; i < n4; i += PB) {
            int4 dv = d4[i];
            int4 sv = s4[i];
            int b0 = dv.x >> BSHIFT, p0 = atomicAdd(&lcur[b0], 1);
            spack[p0] = ((unsigned int)sv.x << BSHIFT) | (unsigned int)(dv.x & (BSZ - 1));
            sbkt[p0] = (unsigned short)b0;
            int b1 = dv.y >> BSHIFT, p1 = atomicAdd(&lcur[b1], 1);
            spack[p1] = ((unsigned int)sv.y << BSHIFT) | (unsigned int)(dv.y & (BSZ - 1));
            sbkt[p1] = (unsigned short)b1;
            int b2 = dv.z >> BSHIFT, p2 = atomicAdd(&lcur[b2], 1);
            spack[p2] = ((unsigned int)sv.z << BSHIFT) | (unsigned int)(dv.z & (BSZ - 1));
            sbkt[p2] = (unsigned short)b2;
            int b3 = dv.w >> BSHIFT, p3 = atomicAdd(&lcur[b3], 1);
            spack[p3] = ((unsigned int)sv.w << BSHIFT) | (unsigned int)(dv.w & (BSZ - 1));
            sbkt[p3] = (unsigned short)b3;
        }
        for (int i = bs + (n4 << 2) + t; i < be; i += PB) {
            int d = dst[i];
            int b = d >> BSHIFT;
            int pos = atomicAdd(&lcur[b], 1);
            spack[pos] = ((unsigned int)src[i] << BSHIFT) | (unsigned int)(d & (BSZ - 1));
            sbkt[pos] = (unsigned short)b;
        }
        __syncthreads();
        // flush: direct bucket lookup, per-bucket contiguous global segments
        for (int j = t; j < cnt; j += PB) {
            int b = sbkt[j];
            bpack[gcur[b] + (j - loff[b])] = spack[j];
        }
        __syncthreads();
        for (int b = t; b < NB; b += PB)
            gcur[b] += loff[b + 1] - loff[b];
        __syncthreads();
    }
}

// shared accumulate body: stream bpack (2x uint4 unroll = 8 gathers in flight)
__device__ __forceinline__ void acc_body(const unsigned int* __restrict__ bpack,
                                         int lo, int hi,
                                         const float* __restrict__ val,
                                         float* acc) {
    int head = min((4 - (lo & 3)) & 3, hi - lo);
    for (int i = lo + (int)threadIdx.x; i < lo + head; i += blockDim.x) {
        unsigned int w = bpack[i];
        atomicAdd(&acc[w & (BSZ - 1)], val[w >> BSHIFT]);
    }
    int lo4 = lo + head;
    int n4 = (hi - lo4) >> 2;
    const uint4* p4 = (const uint4*)(bpack + lo4);
    int i = threadIdx.x;
    int bd = blockDim.x;
    for (; i + bd < n4; i += 2 * bd) {
        uint4 wa = p4[i];
        uint4 wb = p4[i + bd];
        float va0 = val[wa.x >> BSHIFT], va1 = val[wa.y >> BSHIFT];
        float va2 = val[wa.z >> BSHIFT], va3 = val[wa.w >> BSHIFT];
        float vb0 = val[wb.x >> BSHIFT], vb1 = val[wb.y >> BSHIFT];
        float vb2 = val[wb.z >> BSHIFT], vb3 = val[wb.w >> BSHIFT];
        atomicAdd(&acc[wa.x & (BSZ - 1)], va0);
        atomicAdd(&acc[wa.y & (BSZ - 1)], va1);
        atomicAdd(&acc[wa.z & (BSZ - 1)], va2);
        atomicAdd(&acc[wa.w & (BSZ - 1)], va3);
        atomicAdd(&acc[wb.x & (BSZ - 1)], vb0);
        atomicAdd(&acc[wb.y & (BSZ - 1)], vb1);
        atomicAdd(&acc[wb.z & (BSZ - 1)], vb2);
        atomicAdd(&acc[wb.w & (BSZ - 1)], vb3);
    }
    for (; i < n4; i += bd) {
        uint4 w = p4[i];
        atomicAdd(&acc[w.x & (BSZ - 1)], val[w.x >> BSHIFT]);
        atomicAdd(&acc[w.y & (BSZ - 1)], val[w.y >> BSHIFT]);
        atomicAdd(&acc[w.z & (BSZ - 1)], val[w.z >> BSHIFT]);
        atomicAdd(&acc[w.w & (BSZ - 1)], val[w.w >> BSHIFT]);
    }
    for (int j = lo4 + (n4 << 2) + (int)threadIdx.x; j < hi; j += blockDim.x) {
        unsigned int w = bpack[j];
        atomicAdd(&acc[w & (BSZ - 1)], val[w >> BSHIFT]);
    }
}

// ACC-partial: 2 blocks per bucket, each accumulates half the edge range into
// LDS, then flushes its 2048-node partial with coalesced plain stores.
__global__ void k_accp(const unsigned int* __restrict__ bpack,
                       const int* __restrict__ base,
                       const float* __restrict__ val,
                       float* __restrict__ partial, int nN) {
    __shared__ float acc[BSZ];
    for (int j = threadIdx.x; j < BSZ; j += blockDim.x) acc[j] = 0.0f;
    __syncthreads();
    int bid = blockIdx.x;
    int b = bid >> 1;
    int s = bid & 1;
    int lo = base[b], hi = base[b + 1];
    int mid = (lo + hi) >> 1;
    int rlo = s ? mid : lo;
    int rhi = s ? hi : mid;
    acc_body(bpack, rlo, rhi, val, acc);
    __syncthreads();
    float* dstp = partial + (size_t)s * nN;
    int node0 = b << BSHIFT;
    int lim = min(BSZ, nN - node0);
    int l4 = lim >> 2;
    float4* d4 = (float4*)(dstp + node0);
    const float4* a4 = (const float4*)acc;
    for (int j = threadIdx.x; j < l4; j += blockDim.x) d4[j] = a4[j];
    for (int j = (l4 << 2) + (int)threadIdx.x; j < lim; j += blockDim.x)
        dstp[node0 + j] = acc[j];
}

// M1: t[i] = norm * sum_j relu((p0+p1)*norm*W1j + b1j) * W2j
__global__ void k_merge1(const float* __restrict__ partial,
                         const float* __restrict__ norm,
                         const float* __restrict__ W1, const float* __restrict__ b1,
                         const float* __restrict__ W2,
                         float* __restrict__ t, int nN) {
    float w10 = W1[0], w11 = W1[1], w12 = W1[2];
    float b10 = b1[0], b11 = b1[1], b12 = b1[2];
    float w20 = W2[0], w21 = W2[1], w22 = W2[2];
    const float* p0 = partial;
    const float* p1 = partial + nN;
    int stride = gridDim.x * blockDim.x;
    for (int i = blockIdx.x * blockDim.x + threadIdx.x; i < nN; i += stride) {
        float nv = norm[i];
        float s = (p0[i] + p1[i]) * nv;
        float h0 = fmaxf(fmaf(s, w10, b10), 0.0f);
        float h1 = fmaxf(fmaf(s, w11, b11), 0.0f);
        float h2 = fmaxf(fmaf(s, w12, b12), 0.0f);
        t[i] = nv * (h0 * w20 + h1 * w21 + h2 * w22);
    }
}

// M2: out[i] = relu((p0+p1)*norm + b2)
__global__ void k_merge2(const float* __restrict__ partial,
                         const float* __restrict__ norm,
                         const float* __restrict__ b2,
                         float* __restrict__ out, int nN) {
    float bb = b2[0];
    const float* p0 = partial;
    const float* p1 = partial + nN;
    int stride = gridDim.x * blockDim.x;
    for (int i = blockIdx.x * blockDim.x + threadIdx.x; i < nN; i += stride)
        out[i] = fmaxf((p0[i] + p1[i]) * norm[i] + bb, 0.0f);
}

// ---------------- fallback: direct device-scope atomic scatter ----------------
__global__ void k_edge_scatter(const int* __restrict__ src, const int* __restrict__ dst,
                               const float* __restrict__ val, float* __restrict__ agg,
                               int nE) {
    int stride = gridDim.x * blockDim.x;
    for (int e = blockIdx.x * blockDim.x + threadIdx.x; e < nE; e += stride)
        atomicAdd(&agg[dst[e]], val[src[e]]);
}

static inline size_t align256(size_t x) { return (x + 255) & ~(size_t)255; }

extern "C" void kernel_launch(void* const* d_in, const int* in_sizes, int n_in,
                              void* d_out, int out_size, void* d_ws, size_t ws_size,
                              hipStream_t stream) {
    const float* feat = (const float*)d_in[0];
    const float* norm = (const float*)d_in[1];
    const int*   src  = (const int*)d_in[2];
    const int*   dst  = (const int*)d_in[3];
    const float* W1   = (const float*)d_in[4];
    const float* b1   = (const float*)d_in[5];
    const float* W2   = (const float*)d_in[6];
    const float* b2   = (const float*)d_in[7];
    float* out = (float*)d_out;

    int nN = in_sizes[0];
    int nE = in_sizes[2];
    int NB = (nN + BSZ - 1) >> BSHIFT;

    // workspace layout
    char* p = (char*)d_ws;
    size_t off = 0;
    float* g1   = (float*)(p + off); off = align256(off + (size_t)nN * 4);
    float* agg1 = (float*)(p + off); off = align256(off + (size_t)nN * 4);
    float* partial = (float*)(p + off); off = align256(off + 2 * (size_t)nN * 4);
    int* base     = (int*)(p + off); off = align256(off + (size_t)(NB + 1) * 4);
    int* tot      = (int*)(p + off); off = align256(off + (size_t)NB * 4);
    float* agg2   = (float*)(p + off);                        // fallback only
    int* counts   = (int*)(p + off); off = align256(off + (size_t)NB * NBIN_BLOCKS * 4);
    int* chunkpre = (int*)(p + off); off = align256(off + (size_t)NB * NBIN_BLOCKS * 4);
    unsigned int* bpack = (unsigned int*)(p + off); off = align256(off + (size_t)nE * 4);
    size_t need = off;

    const int BLK = 256;
    int nodeBlocks = (nN + BLK - 1) / BLK;
    if (nodeBlocks > 2048) nodeBlocks = 2048;

    bool packed_ok = ((size_t)nN <= ((size_t)1 << (32 - BSHIFT))) && (NB <= NBMAX);
    if (ws_size >= need && packed_ok) {
        // chunk: multiple of 4 so int4 loads stay aligned
        int chunk = (nE + NBIN_BLOCKS - 1) / NBIN_BLOCKS;
        chunk = (chunk + 3) & ~3;
        size_t ldsNB = (size_t)NB * 4;

        k1b<<<nodeBlocks, BLK, 0, stream>>>(feat, norm, g1, nN);
        k_hist<<<NBIN_BLOCKS, 512, ldsNB, stream>>>(dst, nE, NB, chunk, counts);
        k_bucketscan<<<NB, 256, 0, stream>>>(counts, chunkpre, tot);
        k_exscan<<<1, 1024, 0, stream>>>(tot, NB, base);
        k_place2<<<NBIN_BLOCKS, PB, 0, stream>>>(src, dst, nE, NB, chunk,
                                                 chunkpre, base, bpack);
        k_accp<<<2 * NB, 512, 0, stream>>>(bpack, base, g1, partial, nN);
        k_merge1<<<nodeBlocks, BLK, 0, stream>>>(partial, norm, W1, b1, W2, agg1, nN);
        k_accp<<<2 * NB, 512, 0, stream>>>(bpack, base, agg1, partial, nN);
        k_merge2<<<nodeBlocks, BLK, 0, stream>>>(partial, norm, b2, out, nN);
    } else {
        // fallback: direct atomic scatter (round-1 path)
        int edgeBlocks = 2048;
        k1_prep<<<nodeBlocks, BLK, 0, stream>>>(feat, norm, g1, agg1, agg2, nN);
        k_edge_scatter<<<edgeBlocks, BLK, 0, stream>>>(src, dst, g1, agg1, nE);
        k3_mid<<<nodeBlocks, BLK, 0, stream>>>(agg1, norm, W1, b1, W2, g1, nN);
        k_edge_scatter<<<edgeBlocks, BLK, 0, stream>>>(src, dst, g1, agg2, nE);
        k5_out<<<nodeBlocks, BLK, 0, stream>>>(agg2, norm, b2, out, nN);
    }
}